// Round 3
// baseline (5122.923 us; speedup 1.0000x reference)
//
#include <hip/hip_runtime.h>
#include <math.h>

#define NW     64        // workgroups (proven co-resident in round 1)
#define NT     256       // threads per workgroup
#define H      256
#define CTX    128
#define V      33
#define T      220
#define BATCH  1024
#define HBSTR  768       // 3*H, one h-buffer (all layers)

// ---- workspace layout (float offsets) ----
// [0..63]   flags[64] barrier slots (u32, monotonic ordinals)
#define WS_EMB 64                      // [V][1024] precomputed layer0 x-part + biases
#define WS_HB  (WS_EMB + V*1024)       // [2][3][H] double-buffered h
#define WS_PR  (WS_HB + 2*3*H)         // [T][V] compact predictions
// total = 64 + 33792 + 1536 + 7260 = 42652 floats (~167 KB)

__device__ __forceinline__ float gld(const float* p) {
  return __hip_atomic_load(p, __ATOMIC_RELAXED, __HIP_MEMORY_SCOPE_AGENT);
}
__device__ __forceinline__ void gst(float* p, float v) {
  __hip_atomic_store(p, v, __ATOMIC_RELAXED, __HIP_MEMORY_SCOPE_AGENT);
}
__device__ __forceinline__ float sigf(float x) { return 1.f / (1.f + expf(-x)); }

__device__ __forceinline__ float red16(float a) {
  #pragma unroll
  for (int m = 8; m; m >>= 1) a += __shfl_xor(a, m, 16);
  return a;
}

// dot of 16 register-resident weights with x[lane*16..lane*16+16) from LDS
__device__ __forceinline__ float dot16r(const float4* __restrict__ w,
                                        const float* __restrict__ xsh, int lane) {
  const float4* x4 = reinterpret_cast<const float4*>(xsh) + lane * 4;
  float a = 0.f;
  #pragma unroll
  for (int m = 0; m < 4; ++m) {
    float4 W = w[m], X = x4[m];
    a += W.x * X.x + W.y * X.y + W.z * X.z + W.w * X.w;
  }
  return a;
}

// flag-array grid barrier: parallel release-store arrivals to distinct slots
// (no RMW serialization), wave-0 acquire-poll of 64 words, monotonic ordinals.
__device__ __forceinline__ void gbar(unsigned* flags, int tid, int wg, unsigned ord) {
  __syncthreads();   // all waves done with prior reads; wave0's stores drain via release
  if (tid == 0)
    __hip_atomic_store(flags + wg, ord, __ATOMIC_RELEASE, __HIP_MEMORY_SCOPE_AGENT);
  if (tid < NW) {
    unsigned v;
    do {
      v = __hip_atomic_load(flags + tid, __ATOMIC_ACQUIRE, __HIP_MEMORY_SCOPE_AGENT);
    } while (__any(v < ord));
  }
  __syncthreads();
}

// redundant per-WG classifier: f = relu(W1[:,:256].x + b1); logits = W2.f + b2
__device__ __forceinline__ void classifier_logits(
    const float* __restrict__ W1, const float* __restrict__ b1,
    const float* __restrict__ W2, const float* __restrict__ b2,
    const float* __restrict__ xsh, float* __restrict__ fsh,
    float* __restrict__ lsh, int tid, int r, int lane) {
  const float4* x4 = reinterpret_cast<const float4*>(xsh) + lane * 4;
  const float4 X0 = x4[0], X1 = x4[1], X2 = x4[2], X3 = x4[3];
  #pragma unroll 4
  for (int p = 0; p < 16; ++p) {
    const int row = p * 16 + r;
    const float4* w4 = reinterpret_cast<const float4*>(
        W1 + (size_t)row * (H + CTX)) + lane * 4;
    const float4 A = w4[0], B = w4[1], C = w4[2], D = w4[3];
    float a = A.x*X0.x + A.y*X0.y + A.z*X0.z + A.w*X0.w
            + B.x*X1.x + B.y*X1.y + B.z*X1.z + B.w*X1.w
            + C.x*X2.x + C.y*X2.y + C.z*X2.z + C.w*X2.w
            + D.x*X3.x + D.y*X3.y + D.z*X3.z + D.w*X3.w;
    a = red16(a);
    if (lane == 0) fsh[row] = fmaxf(a + b1[row], 0.f);
  }
  __syncthreads();
  const int v = tid >> 2, s = tid & 3;          // 4 lanes per logit
  if (v < V) {
    const float4* wv = reinterpret_cast<const float4*>(W2 + (size_t)v * H) + s * 16;
    const float4* fv = reinterpret_cast<const float4*>(fsh) + s * 16;
    float a = 0.f;
    #pragma unroll
    for (int m = 0; m < 16; ++m) {
      float4 Wq = wv[m], Fq = fv[m];
      a += Wq.x*Fq.x + Wq.y*Fq.y + Wq.z*Fq.z + Wq.w*Fq.w;
    }
    a += __shfl_xor(a, 1, 4);
    a += __shfl_xor(a, 2, 4);
    if (s == 0) lsh[v] = a + b2[v];
  }
  __syncthreads();
}

__global__ __launch_bounds__(NT) void speller_persistent(
    const float* __restrict__ embed,     // [V][H]
    const float* __restrict__ Wih0,      // [4H][H+CTX]
    const float* __restrict__ Wih_rest,  // [2][4H][H]
    const float* __restrict__ Whh,       // [3][4H][H]
    const float* __restrict__ bih,       // [3][4H]
    const float* __restrict__ bhh,       // [3][4H]
    const float* __restrict__ W1,        // [H][H+CTX]
    const float* __restrict__ b1,        // [H]
    const float* __restrict__ W2,        // [V][H]
    const float* __restrict__ b2,        // [V]
    const float* __restrict__ h0,        // [3][H]
    const float* __restrict__ c0,        // [3][H]
    float* __restrict__ ws)
{
  __shared__ __align__(16) float sh_emb[V * H];   // precompute only (33 KB)
  __shared__ __align__(16) float sh_x[H];
  __shared__ __align__(16) float sh_h[H];
  __shared__ __align__(16) float sh_f[H];
  __shared__ float sh_g[16];
  __shared__ float sh_logits[V];
  __shared__ int   sh_char;

  const int tid  = threadIdx.x, wg = blockIdx.x;
  const int r    = tid >> 4, lane = tid & 15;   // 16 rows x 16 lanes
  const int gate = r >> 2,  jj   = r & 3;
  const int wrow = gate * H + wg * 4 + jj;      // gate-row index in [0,1024)

  unsigned* flags = reinterpret_cast<unsigned*>(ws);   // [64]
  float* EMB = ws + WS_EMB;
  float* HB  = ws + WS_HB;
  float* PR  = ws + WS_PR;

  // ---- register-resident LSTM weights: 16 cols of this thread's row ----
  float4 w_hh0[4], w_ih1[4], w_hh1[4], w_ih2[4], w_hh2[4];
  {
    const float4* p;
    p = reinterpret_cast<const float4*>(Whh + (size_t)wrow * H) + lane * 4;
    w_hh0[0]=p[0]; w_hh0[1]=p[1]; w_hh0[2]=p[2]; w_hh0[3]=p[3];
    p = reinterpret_cast<const float4*>(Wih_rest + (size_t)wrow * H) + lane * 4;
    w_ih1[0]=p[0]; w_ih1[1]=p[1]; w_ih1[2]=p[2]; w_ih1[3]=p[3];
    p = reinterpret_cast<const float4*>(Whh + (size_t)(1024 + wrow) * H) + lane * 4;
    w_hh1[0]=p[0]; w_hh1[1]=p[1]; w_hh1[2]=p[2]; w_hh1[3]=p[3];
    p = reinterpret_cast<const float4*>(Wih_rest + (size_t)(1024 + wrow) * H) + lane * 4;
    w_ih2[0]=p[0]; w_ih2[1]=p[1]; w_ih2[2]=p[2]; w_ih2[3]=p[3];
    p = reinterpret_cast<const float4*>(Whh + (size_t)(2048 + wrow) * H) + lane * 4;
    w_hh2[0]=p[0]; w_hh2[1]=p[1]; w_hh2[2]=p[2]; w_hh2[3]=p[3];
  }
  const float bsum1 = bih[1024 + wrow] + bhh[1024 + wrow];
  const float bsum2 = bih[2048 + wrow] + bhh[2048 + wrow];

  // per-WG-owned c state (threads 0..3 hold one h-index each, all layers)
  float c0r = 0.f, c1r = 0.f, c2r = 0.f;
  if (tid < 4) {
    c0r = c0[0 * H + wg * 4 + tid];
    c1r = c0[1 * H + wg * 4 + tid];
    c2r = c0[2 * H + wg * 4 + tid];
  }
  // h init into buffer 1 (= (t=0 - 1) & 1)
  if (wg < 3) gst(HB + HBSTR + wg * H + tid, h0[wg * H + tid]);

  // --- precompute EMB[v][row] = embed[v] . Wih0[row,:256] + bih0[row] + bhh0[row] ---
  for (int i = tid; i < V * H; i += NT) sh_emb[i] = embed[i];
  __syncthreads();
  {
    const int prow = wg * 16 + r;   // each WG owns 16 of the 1024 rows
    const float4* w4 = reinterpret_cast<const float4*>(
        Wih0 + (size_t)prow * (H + CTX) + lane * 16);
    const float4 q0 = w4[0], q1 = w4[1], q2 = w4[2], q3 = w4[3];
    const float bs = bih[prow] + bhh[prow];
    for (int v = 0; v < V; ++v) {
      const float4* e4 = reinterpret_cast<const float4*>(sh_emb + v * H + lane * 16);
      float4 e0 = e4[0], e1 = e4[1], e2 = e4[2], e3 = e4[3];
      float a = q0.x*e0.x + q0.y*e0.y + q0.z*e0.z + q0.w*e0.w
              + q1.x*e1.x + q1.y*e1.y + q1.z*e1.z + q1.w*e1.w
              + q2.x*e2.x + q2.y*e2.y + q2.z*e2.z + q2.w*e2.w
              + q3.x*e3.x + q3.y*e3.y + q3.z*e3.z + q3.w*e3.w;
      a = red16(a);
      if (lane == 0) gst(EMB + v * 1024 + prow, a + bs);
    }
  }
  unsigned ord = 1;
  gbar(flags, tid, wg, ord);

  for (int t = 0; t < T; ++t) {
    const int cur = t & 1, prv = cur ^ 1;

    // ===== Stage A: redundant classifier(t-1) + argmax + layer 0 =====
    sh_h[tid] = gld(HB + prv * HBSTR + 0 * H + tid);          // h0_{t-1}
    if (t > 0) sh_x[tid] = gld(HB + prv * HBSTR + 2 * H + tid); // h2_{t-1}
    __syncthreads();
    float acc = dot16r(w_hh0, sh_h, lane);                    // char-free part of L0
    int chr = 0;
    if (t > 0) {
      classifier_logits(W1, b1, W2, b2, sh_x, sh_f, sh_logits, tid, r, lane);
      if (tid == 0) {
        float best = sh_logits[0]; int bv = 0;
        for (int v = 1; v < V; ++v)
          if (sh_logits[v] > best) { best = sh_logits[v]; bv = v; }
        sh_char = bv;                                         // first-max == jnp.argmax
      }
      __syncthreads();
      chr = sh_char;
      if (wg == 0 && tid < V) PR[(t - 1) * V + tid] = sh_logits[tid];
    }
    acc = red16(acc);
    if (lane == 0) sh_g[r] = acc + EMB[(size_t)chr * 1024 + wrow];
    __syncthreads();
    if (tid < 4) {
      float gi = sh_g[tid], gf = sh_g[4 + tid], gg = sh_g[8 + tid], go = sh_g[12 + tid];
      float cn = sigf(gf) * c0r + sigf(gi) * tanhf(gg);
      c0r = cn;
      gst(HB + cur * HBSTR + 0 * H + wg * 4 + tid, sigf(go) * tanhf(cn));
    }
    gbar(flags, tid, wg, ++ord);

    // ===== Stage B: layer 1 =====
    sh_x[tid] = gld(HB + cur * HBSTR + 0 * H + tid);   // h0_t
    sh_h[tid] = gld(HB + prv * HBSTR + 1 * H + tid);   // h1_{t-1}
    __syncthreads();
    acc = dot16r(w_ih1, sh_x, lane) + dot16r(w_hh1, sh_h, lane);
    acc = red16(acc);
    if (lane == 0) sh_g[r] = acc + bsum1;
    __syncthreads();
    if (tid < 4) {
      float gi = sh_g[tid], gf = sh_g[4 + tid], gg = sh_g[8 + tid], go = sh_g[12 + tid];
      float cn = sigf(gf) * c1r + sigf(gi) * tanhf(gg);
      c1r = cn;
      gst(HB + cur * HBSTR + 1 * H + wg * 4 + tid, sigf(go) * tanhf(cn));
    }
    gbar(flags, tid, wg, ++ord);

    // ===== Stage C: layer 2 =====
    sh_x[tid] = gld(HB + cur * HBSTR + 1 * H + tid);   // h1_t
    sh_h[tid] = gld(HB + prv * HBSTR + 2 * H + tid);   // h2_{t-1}
    __syncthreads();
    acc = dot16r(w_ih2, sh_x, lane) + dot16r(w_hh2, sh_h, lane);
    acc = red16(acc);
    if (lane == 0) sh_g[r] = acc + bsum2;
    __syncthreads();
    if (tid < 4) {
      float gi = sh_g[tid], gf = sh_g[4 + tid], gg = sh_g[8 + tid], go = sh_g[12 + tid];
      float cn = sigf(gf) * c2r + sigf(gi) * tanhf(gg);
      c2r = cn;
      gst(HB + cur * HBSTR + 2 * H + wg * 4 + tid, sigf(go) * tanhf(cn));
    }
    gbar(flags, tid, wg, ++ord);
  }

  // ===== epilogue: logits for t = T-1 (wg0 only; h2 published at last barrier) =====
  if (wg == 0) {
    const int cur = (T - 1) & 1;
    sh_x[tid] = gld(HB + cur * HBSTR + 2 * H + tid);
    __syncthreads();
    classifier_logits(W1, b1, W2, b2, sh_x, sh_f, sh_logits, tid, r, lane);
    if (tid < V) PR[(T - 1) * V + tid] = sh_logits[tid];   // flushed at kernel end
  }
}

// broadcast compact [T][V] predictions to [B][T][V]
__global__ __launch_bounds__(NT) void bcast_kernel(const float* __restrict__ PR,
                                                   float* __restrict__ out) {
  float* o = out + (size_t)blockIdx.x * (T * V);
  for (int i = threadIdx.x; i < T * V; i += NT) o[i] = PR[i];
}

extern "C" void kernel_launch(void* const* d_in, const int* in_sizes, int n_in,
                              void* d_out, int out_size, void* d_ws, size_t ws_size,
                              hipStream_t stream) {
  const float* embed    = (const float*)d_in[1];
  const float* Wih0     = (const float*)d_in[2];
  const float* Wih_rest = (const float*)d_in[3];
  const float* Whh      = (const float*)d_in[4];
  const float* bih      = (const float*)d_in[5];
  const float* bhh      = (const float*)d_in[6];
  const float* W1       = (const float*)d_in[7];
  const float* b1       = (const float*)d_in[8];
  const float* W2       = (const float*)d_in[9];
  const float* b2       = (const float*)d_in[10];
  const float* h0       = (const float*)d_in[11];
  const float* c0       = (const float*)d_in[12];
  float* out = (float*)d_out;
  float* ws  = (float*)d_ws;

  // zero the barrier flags (ws is poisoned 0xAA before every launch)
  hipMemsetAsync(d_ws, 0, 256, stream);

  speller_persistent<<<NW, NT, 0, stream>>>(embed, Wih0, Wih_rest, Whh, bih, bhh,
                                            W1, b1, W2, b2, h0, c0, ws);
  bcast_kernel<<<BATCH, NT, 0, stream>>>(ws + WS_PR, out);
}

// Round 4
// 2382.193 us; speedup vs baseline: 2.1505x; 2.1505x over previous
//
#include <hip/hip_runtime.h>
#include <math.h>

#define NW     64        // workgroups (proven co-resident)
#define NT     256       // threads per workgroup
#define H      256
#define CTX    128
#define V      33
#define T      220
#define BATCH  1024
#define SENT   0xAAAAAAAAu   // harness poison pattern; our sentinel

// ---- workspace layout (float offsets) ----
// [0..63]   startup counter (u32) + pad
#define WS_H0  64                    // [T][H] h0_t exchange
#define WS_H1  (WS_H0 + T*H)         // [T][H] h1_t
#define WS_H2  (WS_H1 + T*H)         // [T][H] h2_t
#define WS_F   (WS_H2 + T*H)         // [T][H] f_t
#define WS_PR  (WS_F  + T*H)         // [T][V] compact predictions
// total = 64 + 4*220*256 + 220*33 = 232,604 floats (~930 KB)

__device__ __forceinline__ float gld(const float* p) {
  return __hip_atomic_load(p, __ATOMIC_RELAXED, __HIP_MEMORY_SCOPE_AGENT);
}
__device__ __forceinline__ void gst(float* p, float v) {
  __hip_atomic_store(p, v, __ATOMIC_RELAXED, __HIP_MEMORY_SCOPE_AGENT);
}
__device__ __forceinline__ float sigf(float x) { return 1.f / (1.f + expf(-x)); }

__device__ __forceinline__ float red16(float a) {
  #pragma unroll
  for (int m = 8; m; m >>= 1) a += __shfl_xor(a, m, 16);
  return a;
}

// dot of 16 register-resident weights with x[lane*16..lane*16+16) from LDS
__device__ __forceinline__ float dot16r(const float4* __restrict__ w,
                                        const float* __restrict__ xsh, int lane) {
  const float4* x4 = reinterpret_cast<const float4*>(xsh) + lane * 4;
  float a = 0.f;
  #pragma unroll
  for (int m = 0; m < 4; ++m) {
    float4 W = w[m], X = x4[m];
    a += W.x * X.x + W.y * X.y + W.z * X.z + W.w * X.w;
  }
  return a;
}

// poll one word until it is no longer the sentinel; returns the data.
__device__ __forceinline__ float pollw(const float* p) {
  float v = gld(p);
  while (__float_as_uint(v) == SENT) v = gld(p);
  return v;
}

__global__ __launch_bounds__(NT) void speller_persistent(
    const float* __restrict__ embed,     // [V][H]
    const float* __restrict__ Wih0,      // [4H][H+CTX]
    const float* __restrict__ Wih_rest,  // [2][4H][H]
    const float* __restrict__ Whh,       // [3][4H][H]
    const float* __restrict__ bih,       // [3][4H]
    const float* __restrict__ bhh,       // [3][4H]
    const float* __restrict__ W1,        // [H][H+CTX]
    const float* __restrict__ b1,        // [H]
    const float* __restrict__ W2,        // [V][H]
    const float* __restrict__ b2,        // [V]
    const float* __restrict__ h0,        // [3][H]
    const float* __restrict__ c0,        // [3][H]
    float* __restrict__ ws)
{
  __shared__ __align__(16) float sh_w[V * H];      // embed (prologue) then W2 (loop)
  __shared__ __align__(16) float sh_h0p[H];        // retained h0_{t-1}
  __shared__ __align__(16) float sh_h1p[H];        // retained h1_{t-1}
  __shared__ __align__(16) float sh_h2p[H];        // retained h2_{t-1}
  __shared__ __align__(16) float sh_fv[H];         // staged f_{t-1}
  __shared__ float sh_emb_tab[V * 16];             // EMB slice for this WG's 16 rows
  __shared__ float sh_b2[V];
  __shared__ float sh_g[16];
  __shared__ float sh_logits[V];
  __shared__ int   sh_char;

  const int tid  = threadIdx.x, wg = blockIdx.x;
  const int r    = tid >> 4, lane = tid & 15;   // 16 rows x 16 lanes
  const int gate = r >> 2,  jj   = r & 3;
  const int wrow = gate * H + wg * 4 + jj;      // gate-row index in [0,1024)

  unsigned* cnt = reinterpret_cast<unsigned*>(ws);
  float* HX0 = ws + WS_H0;
  float* HX1 = ws + WS_H1;
  float* HX2 = ws + WS_H2;
  float* FX  = ws + WS_F;
  float* PR  = ws + WS_PR;

  // ---- register-resident LSTM weights: 16 cols of this thread's row ----
  float4 w_hh0[4], w_ih1[4], w_hh1[4], w_ih2[4], w_hh2[4], w1r[4];
  {
    const float4* p;
    p = reinterpret_cast<const float4*>(Whh + (size_t)wrow * H) + lane * 4;
    w_hh0[0]=p[0]; w_hh0[1]=p[1]; w_hh0[2]=p[2]; w_hh0[3]=p[3];
    p = reinterpret_cast<const float4*>(Wih_rest + (size_t)wrow * H) + lane * 4;
    w_ih1[0]=p[0]; w_ih1[1]=p[1]; w_ih1[2]=p[2]; w_ih1[3]=p[3];
    p = reinterpret_cast<const float4*>(Whh + (size_t)(1024 + wrow) * H) + lane * 4;
    w_hh1[0]=p[0]; w_hh1[1]=p[1]; w_hh1[2]=p[2]; w_hh1[3]=p[3];
    p = reinterpret_cast<const float4*>(Wih_rest + (size_t)(1024 + wrow) * H) + lane * 4;
    w_ih2[0]=p[0]; w_ih2[1]=p[1]; w_ih2[2]=p[2]; w_ih2[3]=p[3];
    p = reinterpret_cast<const float4*>(Whh + (size_t)(2048 + wrow) * H) + lane * 4;
    w_hh2[0]=p[0]; w_hh2[1]=p[1]; w_hh2[2]=p[2]; w_hh2[3]=p[3];
  }
  const float bsum1 = bih[1024 + wrow] + bhh[1024 + wrow];
  const float bsum2 = bih[2048 + wrow] + bhh[2048 + wrow];

  // classifier W1 slice (rows wg*4..wg*4+3) in registers of tid<64
  float b1r = 0.f;
  w1r[0] = w1r[1] = w1r[2] = w1r[3] = float4{0.f, 0.f, 0.f, 0.f};
  if (tid < 64) {
    const int jf = wg * 4 + (tid >> 4);
    b1r = b1[jf];
    const float4* p = reinterpret_cast<const float4*>(W1 + (size_t)jf * (H + CTX)) + lane * 4;
    w1r[0]=p[0]; w1r[1]=p[1]; w1r[2]=p[2]; w1r[3]=p[3];
  }

  // per-WG-owned c state (threads 0..3 hold one h-index each, all layers)
  float c0r = 0.f, c1r = 0.f, c2r = 0.f;
  if (tid < 4) {
    c0r = c0[0 * H + wg * 4 + tid];
    c1r = c0[1 * H + wg * 4 + tid];
    c2r = c0[2 * H + wg * 4 + tid];
  }
  // retained h state init = h0 input
  sh_h0p[tid] = h0[0 * H + tid];
  sh_h1p[tid] = h0[1 * H + tid];
  sh_h2p[tid] = h0[2 * H + tid];
  if (tid < V) sh_b2[tid] = b2[tid];

  // ---- prologue A: embed into LDS, compute per-WG EMB table ----
  for (int i = tid; i < V * H; i += NT) sh_w[i] = embed[i];
  __syncthreads();
  {
    // this WG consumes rows {gate*256 + wg*4 + jj} -> table index r = gate*4+jj
    const float4* w4 = reinterpret_cast<const float4*>(
        Wih0 + (size_t)wrow * (H + CTX) + lane * 16);
    const float4 q0 = w4[0], q1 = w4[1], q2 = w4[2], q3 = w4[3];
    const float bs = bih[wrow] + bhh[wrow];
    for (int v = 0; v < V; ++v) {
      const float4* e4 = reinterpret_cast<const float4*>(sh_w + v * H + lane * 16);
      float4 e0 = e4[0], e1 = e4[1], e2 = e4[2], e3 = e4[3];
      float a = q0.x*e0.x + q0.y*e0.y + q0.z*e0.z + q0.w*e0.w
              + q1.x*e1.x + q1.y*e1.y + q1.z*e1.z + q1.w*e1.w
              + q2.x*e2.x + q2.y*e2.y + q2.z*e2.z + q2.w*e2.w
              + q3.x*e3.x + q3.y*e3.y + q3.z*e3.z + q3.w*e3.w;
      a = red16(a);
      if (lane == 0) sh_emb_tab[v * 16 + r] = a + bs;
    }
  }
  __syncthreads();
  // ---- prologue B: overwrite sh_w with W2 ----
  for (int i = tid; i < V * H; i += NT) sh_w[i] = W2[i];

  // ---- prologue C: poison this WG's producer slots for all t ----
  if (tid < T) {
    const int t = tid;
    const float sf = __uint_as_float(SENT);
    #pragma unroll
    for (int k = 0; k < 4; ++k) {
      gst(HX0 + t * H + wg * 4 + k, sf);
      gst(HX1 + t * H + wg * 4 + k, sf);
      gst(HX2 + t * H + wg * 4 + k, sf);
      gst(FX  + t * H + wg * 4 + k, sf);
    }
  }

  // ---- one startup barrier (round-1-proven counter barrier) ----
  __syncthreads();
  if (tid == 0) {
    __hip_atomic_fetch_add(cnt, 1u, __ATOMIC_RELEASE, __HIP_MEMORY_SCOPE_AGENT);
    while (__hip_atomic_load(cnt, __ATOMIC_ACQUIRE, __HIP_MEMORY_SCOPE_AGENT)
           < (unsigned)NW)
      __builtin_amdgcn_s_sleep(1);
  }
  __syncthreads();

  // =================== time loop: 4 one-hop exchanges/step ===================
  for (int t = 0; t < T; ++t) {
    // ----- Stage A: char-free L0 dot; logits/argmax from f_{t-1}; publish h0_t
    float acc = dot16r(w_hh0, sh_h0p, lane);   // h0_{t-1} retained in LDS
    acc = red16(acc);
    int chr = 0;
    if (t > 0) {
      sh_fv[tid] = pollw(FX + (size_t)(t - 1) * H + tid);
      __syncthreads();
      const int v = tid >> 2, s = tid & 3;     // 4 lanes per logit
      if (v < V) {
        const float4* wv = reinterpret_cast<const float4*>(sh_w + v * H) + s * 16;
        const float4* fq = reinterpret_cast<const float4*>(sh_fv) + s * 16;
        float a = 0.f;
        #pragma unroll
        for (int m = 0; m < 16; ++m) {
          float4 Wq = wv[m], Fq = fq[m];
          a += Wq.x*Fq.x + Wq.y*Fq.y + Wq.z*Fq.z + Wq.w*Fq.w;
        }
        a += __shfl_xor(a, 1, 4);
        a += __shfl_xor(a, 2, 4);
        if (s == 0) sh_logits[v] = a + sh_b2[v];
      }
      __syncthreads();
      if (tid == 0) {
        float best = sh_logits[0]; int bv = 0;
        for (int v2 = 1; v2 < V; ++v2)
          if (sh_logits[v2] > best) { best = sh_logits[v2]; bv = v2; }
        sh_char = bv;                           // first-max == jnp.argmax
      }
      __syncthreads();
      chr = sh_char;
      if (wg == 0 && tid < V) PR[(t - 1) * V + tid] = sh_logits[tid];
    }
    if (lane == 0) sh_g[r] = acc + sh_emb_tab[chr * 16 + r];
    __syncthreads();
    if (tid < 4) {
      float gi = sh_g[tid], gf = sh_g[4 + tid], gg = sh_g[8 + tid], go = sh_g[12 + tid];
      float cn = sigf(gf) * c0r + sigf(gi) * tanhf(gg);
      c0r = cn;
      gst(HX0 + (size_t)t * H + wg * 4 + tid, sigf(go) * tanhf(cn));
    }

    // ----- Stage B: layer 1; poll h0_t, retain in LDS; publish h1_t
    {
      float hv = pollw(HX0 + (size_t)t * H + tid);
      sh_h0p[tid] = hv;                        // becomes h0_t for stage A(t+1)
    }
    __syncthreads();
    acc = dot16r(w_ih1, sh_h0p, lane) + dot16r(w_hh1, sh_h1p, lane);
    acc = red16(acc);
    if (lane == 0) sh_g[r] = acc + bsum1;
    __syncthreads();
    if (tid < 4) {
      float gi = sh_g[tid], gf = sh_g[4 + tid], gg = sh_g[8 + tid], go = sh_g[12 + tid];
      float cn = sigf(gf) * c1r + sigf(gi) * tanhf(gg);
      c1r = cn;
      gst(HX1 + (size_t)t * H + wg * 4 + tid, sigf(go) * tanhf(cn));
    }

    // ----- Stage C: layer 2; poll h1_t; publish h2_t
    {
      float hv = pollw(HX1 + (size_t)t * H + tid);
      sh_h1p[tid] = hv;
    }
    __syncthreads();
    acc = dot16r(w_ih2, sh_h1p, lane) + dot16r(w_hh2, sh_h2p, lane);
    acc = red16(acc);
    if (lane == 0) sh_g[r] = acc + bsum2;
    __syncthreads();
    if (tid < 4) {
      float gi = sh_g[tid], gf = sh_g[4 + tid], gg = sh_g[8 + tid], go = sh_g[12 + tid];
      float cn = sigf(gf) * c2r + sigf(gi) * tanhf(gg);
      c2r = cn;
      gst(HX2 + (size_t)t * H + wg * 4 + tid, sigf(go) * tanhf(cn));
    }

    // ----- Stage D: classifier hidden; poll h2_t; publish f_t (4 rows/WG)
    {
      float hv = pollw(HX2 + (size_t)t * H + tid);
      sh_h2p[tid] = hv;
    }
    __syncthreads();
    if (tid < 64) {
      float a = dot16r(w1r, sh_h2p, lane);
      a = red16(a);
      if (lane == 0)
        gst(FX + (size_t)t * H + wg * 4 + (tid >> 4), fmaxf(a + b1r, 0.f));
    }
    // no sync needed: sh_h2p next touched by stage C(t+1) after its own syncs
  }

  // ===== epilogue: logits for t = T-1 (wg0 only) =====
  if (wg == 0) {
    sh_fv[tid] = pollw(FX + (size_t)(T - 1) * H + tid);
    __syncthreads();
    const int v = tid >> 2, s = tid & 3;
    if (v < V) {
      const float4* wv = reinterpret_cast<const float4*>(sh_w + v * H) + s * 16;
      const float4* fq = reinterpret_cast<const float4*>(sh_fv) + s * 16;
      float a = 0.f;
      #pragma unroll
      for (int m = 0; m < 16; ++m) {
        float4 Wq = wv[m], Fq = fq[m];
        a += Wq.x*Fq.x + Wq.y*Fq.y + Wq.z*Fq.z + Wq.w*Fq.w;
      }
      a += __shfl_xor(a, 1, 4);
      a += __shfl_xor(a, 2, 4);
      if (s == 0) sh_logits[v] = a + sh_b2[v];
    }
    __syncthreads();
    if (tid < V) PR[(T - 1) * V + tid] = sh_logits[tid];  // flushed at kernel end
  }
}

// broadcast compact [T][V] predictions to [B][T][V]
__global__ __launch_bounds__(NT) void bcast_kernel(const float* __restrict__ PR,
                                                   float* __restrict__ out) {
  float* o = out + (size_t)blockIdx.x * (T * V);
  for (int i = threadIdx.x; i < T * V; i += NT) o[i] = PR[i];
}

extern "C" void kernel_launch(void* const* d_in, const int* in_sizes, int n_in,
                              void* d_out, int out_size, void* d_ws, size_t ws_size,
                              hipStream_t stream) {
  const float* embed    = (const float*)d_in[1];
  const float* Wih0     = (const float*)d_in[2];
  const float* Wih_rest = (const float*)d_in[3];
  const float* Whh      = (const float*)d_in[4];
  const float* bih      = (const float*)d_in[5];
  const float* bhh      = (const float*)d_in[6];
  const float* W1       = (const float*)d_in[7];
  const float* b1       = (const float*)d_in[8];
  const float* W2       = (const float*)d_in[9];
  const float* b2       = (const float*)d_in[10];
  const float* h0       = (const float*)d_in[11];
  const float* c0       = (const float*)d_in[12];
  float* out = (float*)d_out;
  float* ws  = (float*)d_ws;

  // zero the startup counter (ws is poisoned 0xAA before every launch)
  hipMemsetAsync(d_ws, 0, 256, stream);

  speller_persistent<<<NW, NT, 0, stream>>>(embed, Wih0, Wih_rest, Whh, bih, bhh,
                                            W1, b1, W2, b2, h0, c0, ws);
  bcast_kernel<<<BATCH, NT, 0, stream>>>(ws + WS_PR, out);
}